// Round 2
// baseline (388.502 us; speedup 1.0000x reference)
//
#include <hip/hip_runtime.h>
#include <hip/hip_bf16.h>

// Problem constants (from setup_inputs: B=16, L=4096, D=1024)
constexpr int B = 16;
constexpr int L = 4096;
constexpr int D = 1024;
constexpr int P = (L - 2) / 2;          // 2047 output positions per batch

constexpr int WAVES_PER_BATCH = 512;    // power of 2
constexpr int CHUNK = 4;                // positions per wave (512*4 >= 2047)

// One wave (64 lanes) per chain of CHUNK consecutive positions.
// Lane l owns float4 indices {j*64 + l : j=0..3} of each 1024-float row
// (coalesced per instruction). No __syncthreads anywhere.
// The "right" row of position p is reused in registers as the "left" row
// of position p+1, so each position costs 2 row-loads instead of 3.
__global__ __launch_bounds__(256) void gated_cnn_kernel(
    const float* __restrict__ X,
    const float* __restrict__ G,
    const float* __restrict__ Gb,
    float* __restrict__ out) {
  const int gtid = blockIdx.x * 256 + threadIdx.x;
  const int wid  = gtid >> 6;           // 0 .. 8191
  const int lane = gtid & 63;

  const int b  = wid >> 9;              // wid / WAVES_PER_BATCH
  const int c  = wid & (WAVES_PER_BATCH - 1);
  const int p0 = c * CHUNK;             // first position of this wave's chain

  // Cache gate weights for this lane's 16 channels in registers.
  // G is (D,2) row-major; float4 index f4 covers channels 4*f4..4*f4+3,
  // needing G float4s 2*f4 and 2*f4+1.
  float4 gA[4], gB[4];
  #pragma unroll
  for (int j = 0; j < 4; ++j) {
    const int f4 = j * 64 + lane;
    gA[j] = ((const float4*)G)[2 * f4];
    gB[j] = ((const float4*)G)[2 * f4 + 1];
  }
  const float gb0 = Gb[0];
  const float gb1 = Gb[1];

  const float* xb = X + (size_t)b * L * D;
  float* ob = out + (size_t)b * P * D;

  // Initial left row: row 2*p0.
  float4 lf[4];
  {
    const float4* lrow = (const float4*)(xb + (size_t)(2 * p0) * D);
    #pragma unroll
    for (int j = 0; j < 4; ++j) lf[j] = lrow[j * 64 + lane];
  }

  for (int i = 0; i < CHUNK; ++i) {
    const int p = p0 + i;
    if (p >= P) break;                  // wave-uniform guard

    const float4* mrow = (const float4*)(xb + (size_t)(2 * p + 1) * D);
    const float4* rrow = (const float4*)(xb + (size_t)(2 * p + 2) * D);
    float4 m[4], rt[4];
    #pragma unroll
    for (int j = 0; j < 4; ++j) {
      m[j]  = mrow[j * 64 + lane];
      rt[j] = rrow[j * 64 + lane];
    }

    // Per-lane partial dots for the two gate logits.
    float s0 = 0.f, s1 = 0.f;
    #pragma unroll
    for (int j = 0; j < 4; ++j) {
      s0 += m[j].x * gA[j].x + m[j].y * gA[j].z + m[j].z * gB[j].x + m[j].w * gB[j].z;
      s1 += m[j].x * gA[j].y + m[j].y * gA[j].w + m[j].z * gB[j].y + m[j].w * gB[j].w;
    }

    // 64-lane butterfly: every lane ends with the full sums (no LDS needed).
    #pragma unroll
    for (int off = 1; off < 64; off <<= 1) {
      s0 += __shfl_xor(s0, off, 64);
      s1 += __shfl_xor(s1, off, 64);
    }

    const float t0 = s0 + gb0;
    const float t1 = s1 + gb1;
    const float mx = fmaxf(t0, t1);
    const float e0 = __expf(t0 - mx);
    const float e1 = __expf(t1 - mx);
    const float inv = 1.0f / (e0 + e1);
    const float g0 = e0 * inv;
    const float g1 = e1 * inv;

    float4* orow = (float4*)(ob + (size_t)p * D);
    #pragma unroll
    for (int j = 0; j < 4; ++j) {
      float4 r;
      r.x = lf[j].x * g0 + rt[j].x * g1;
      r.y = lf[j].y * g0 + rt[j].y * g1;
      r.z = lf[j].z * g0 + rt[j].z * g1;
      r.w = lf[j].w * g0 + rt[j].w * g1;
      orow[j * 64 + lane] = r;
      lf[j] = rt[j];                    // right row becomes next left row
    }
  }
}

extern "C" void kernel_launch(void* const* d_in, const int* in_sizes, int n_in,
                              void* d_out, int out_size, void* d_ws, size_t ws_size,
                              hipStream_t stream) {
  const float* X  = (const float*)d_in[0];
  const float* G  = (const float*)d_in[1];
  const float* Gb = (const float*)d_in[2];
  float* out = (float*)d_out;

  // 16 batches * 512 waves = 8192 waves = 2048 blocks of 256 threads.
  gated_cnn_kernel<<<dim3(B * WAVES_PER_BATCH / 4), dim3(256), 0, stream>>>(X, G, Gb, out);
}